// Round 2
// baseline (2209.792 us; speedup 1.0000x reference)
//
#include <hip/hip_runtime.h>
#include <stdint.h>

#define B_ 32
#define H_ 64
#define W_ 64
#define D_ 256
#define U_ 512
#define KTOT 1280  // 256 (x) + 512 (h_up) + 512 (h_left)

typedef __attribute__((ext_vector_type(8))) _Float16 half8;
typedef __attribute__((ext_vector_type(8))) unsigned short ushort8;
typedef __attribute__((ext_vector_type(4))) float f32x4;

__device__ __forceinline__ unsigned short f2h(float f) {
    _Float16 h = (_Float16)f;  // RNE
    return __builtin_bit_cast(unsigned short, h);
}

// Build WcT[n][k] (fp16), n in [0,512), k in [0,1280): stacked [wax; w0; w1] transposed.
__global__ void prep_kernel(const float* __restrict__ wax,
                            const float* __restrict__ w0,
                            const float* __restrict__ w1,
                            unsigned short* __restrict__ wcT) {
    int n = blockIdx.x;  // 512 blocks
    for (int k = threadIdx.x; k < KTOT; k += blockDim.x) {
        float v;
        if (k < D_)            v = wax[(size_t)k * U_ + n];
        else if (k < D_ + U_)  v = w0[(size_t)(k - D_) * U_ + n];
        else                   v = w1[(size_t)(k - D_ - U_) * U_ + n];
        wcT[(size_t)n * KTOT + k] = f2h(v);
    }
}

// One block = (one cell of diagonal d) x (128-column N-chunk).
// A = [x_ij (K 0..255) | h_up (256..767) | h_left (768..1279)], M=32 batch rows.
__global__ __launch_bounds__(256) void cell_kernel(
    const float* __restrict__ x,
    const unsigned short* __restrict__ wcT,
    const unsigned short* __restrict__ frontR,
    unsigned short* __restrict__ frontW,
    const float* __restrict__ ba,
    float* __restrict__ out,
    int d)
{
    __shared__ unsigned short smA[32 * 128];  // 8 KB, XOR-swizzled rows

    const int cell   = blockIdx.x >> 2;
    const int nchunk = blockIdx.x & 3;
    const int jlo = (d > H_ - 1) ? (d - (H_ - 1)) : 0;
    const int j = jlo + cell;
    const int i = d - j;
    const bool has_up   = (i > 0);
    const bool has_left = (j > 0);

    const int t    = threadIdx.x;
    const int lane = t & 63;
    const int wv   = t >> 6;    // wave 0..3 -> 32 N-cols each
    const int l15  = lane & 15;
    const int lh   = lane >> 4; // 0..3 (k-group)

    f32x4 zero = {0.f, 0.f, 0.f, 0.f};
    f32x4 acc[2][2];
    acc[0][0] = zero; acc[0][1] = zero; acc[1][0] = zero; acc[1][1] = zero;

    const int row = t >> 3;  // staging: 0..31
    const int c8  = t & 7;   // staging: 16-elem column chunk
    char* smb = reinterpret_cast<char*>(smA);

    for (int ck = 0; ck < 10; ++ck) {
        if (ck >= 2 && ck < 6 && !has_up) continue;    // uniform per block
        if (ck >= 6 && !has_left) continue;
        __syncthreads();  // previous chunk's LDS reads done before overwrite

        // ---- stage 32x128 fp16 chunk into LDS (swizzle: byte ^= (row&7)<<4) ----
        const int byte0 = row * 256 + c8 * 32;
        const int swz = (row & 7) << 4;
        if (ck < 2) {
            const float4* src = reinterpret_cast<const float4*>(
                x + (((size_t)row * H_ + i) * W_ + j) * D_ + ck * 128 + c8 * 16);
            float4 f0 = src[0], f1 = src[1], f2 = src[2], f3 = src[3];
            ushort8 o0, o1;
            o0[0]=f2h(f0.x); o0[1]=f2h(f0.y); o0[2]=f2h(f0.z); o0[3]=f2h(f0.w);
            o0[4]=f2h(f1.x); o0[5]=f2h(f1.y); o0[6]=f2h(f1.z); o0[7]=f2h(f1.w);
            o1[0]=f2h(f2.x); o1[1]=f2h(f2.y); o1[2]=f2h(f2.z); o1[3]=f2h(f2.w);
            o1[4]=f2h(f3.x); o1[5]=f2h(f3.y); o1[6]=f2h(f3.z); o1[7]=f2h(f3.w);
            *reinterpret_cast<ushort8*>(smb + (byte0 ^ swz)) = o0;
            *reinterpret_cast<ushort8*>(smb + ((byte0 + 16) ^ swz)) = o1;
        } else {
            const int up = (ck < 6) ? 1 : 0;
            const int jj = up ? j : (j - 1);
            const int kl = up ? (ck - 2) * 128 : (ck - 6) * 128;
            const ushort8* src = reinterpret_cast<const ushort8*>(
                frontR + ((size_t)jj * 32 + row) * U_ + kl + c8 * 16);
            ushort8 v0 = src[0], v1 = src[1];
            *reinterpret_cast<ushort8*>(smb + (byte0 ^ swz)) = v0;
            *reinterpret_cast<ushort8*>(smb + ((byte0 + 16) ^ swz)) = v1;
        }
        __syncthreads();

        // ---- fragments: A from LDS (swizzled), B direct from L2-resident WcT ----
        const int kbase = ck * 128;
        half8 af[2][4];
        half8 bfr[2][4];
        #pragma unroll
        for (int ks = 0; ks < 4; ++ks) {
            #pragma unroll
            for (int mt = 0; mt < 2; ++mt) {
                int r2 = mt * 16 + l15;
                int byt = r2 * 256 + ks * 64 + lh * 16;
                byt ^= (r2 & 7) << 4;
                af[mt][ks] = *reinterpret_cast<const half8*>(smb + byt);
            }
            #pragma unroll
            for (int nt = 0; nt < 2; ++nt) {
                int ncol = nchunk * 128 + wv * 32 + nt * 16 + l15;
                bfr[nt][ks] = *reinterpret_cast<const half8*>(
                    wcT + (size_t)ncol * KTOT + kbase + ks * 32 + lh * 8);
            }
        }
        #pragma unroll
        for (int ks = 0; ks < 4; ++ks) {
            acc[0][0] = __builtin_amdgcn_mfma_f32_16x16x32_f16(af[0][ks], bfr[0][ks], acc[0][0], 0, 0, 0);
            acc[0][1] = __builtin_amdgcn_mfma_f32_16x16x32_f16(af[0][ks], bfr[1][ks], acc[0][1], 0, 0, 0);
            acc[1][0] = __builtin_amdgcn_mfma_f32_16x16x32_f16(af[1][ks], bfr[0][ks], acc[1][0], 0, 0, 0);
            acc[1][1] = __builtin_amdgcn_mfma_f32_16x16x32_f16(af[1][ks], bfr[1][ks], acc[1][1], 0, 0, 0);
        }
    }

    // ---- epilogue: +ba, tanh, write frontier (fp16) and final output (fp32) ----
    const bool last = (i == H_ - 1) && (j == W_ - 1);
    #pragma unroll
    for (int mt = 0; mt < 2; ++mt) {
        #pragma unroll
        for (int nt = 0; nt < 2; ++nt) {
            int ncol = nchunk * 128 + wv * 32 + nt * 16 + l15;
            float bav = ba[ncol];
            #pragma unroll
            for (int r = 0; r < 4; ++r) {
                int brow = mt * 16 + lh * 4 + r;  // batch index (C/D: row=(lane>>4)*4+reg)
                float v = acc[mt][nt][r] + bav;
                v = fminf(fmaxf(v, -15.f), 15.f);
                float e = __expf(2.f * v);
                float th = (e - 1.f) / (e + 1.f);
                frontW[((size_t)j * 32 + brow) * U_ + ncol] = f2h(th);
                if (last) out[(size_t)brow * U_ + ncol] = th;
            }
        }
    }
}

extern "C" void kernel_launch(void* const* d_in, const int* in_sizes, int n_in,
                              void* d_out, int out_size, void* d_ws, size_t ws_size,
                              hipStream_t stream) {
    const float* x   = (const float*)d_in[0];
    const float* wax = (const float*)d_in[1];
    const float* w0  = (const float*)d_in[2];
    const float* w1  = (const float*)d_in[3];
    const float* ba  = (const float*)d_in[4];
    float* out = (float*)d_out;

    // Workspace layout: WcT (1.25 MB) | frontierA (2 MB) | frontierB (2 MB)
    unsigned short* wcT = (unsigned short*)d_ws;
    size_t wct_bytes = (size_t)U_ * KTOT * sizeof(unsigned short);
    size_t off = (wct_bytes + 4095) & ~(size_t)4095;
    unsigned short* frontA = (unsigned short*)((char*)d_ws + off);
    unsigned short* frontB = frontA + (size_t)W_ * 32 * U_;

    prep_kernel<<<dim3(U_), dim3(256), 0, stream>>>(wax, w0, w1, wcT);

    for (int d = 0; d < H_ + W_ - 1; ++d) {
        int jlo = (d > H_ - 1) ? d - (H_ - 1) : 0;
        int jhi = (d < W_ - 1) ? d : W_ - 1;
        int nd = jhi - jlo + 1;
        const unsigned short* R = (d & 1) ? frontB : frontA;
        unsigned short* Wr      = (d & 1) ? frontA : frontB;
        cell_kernel<<<dim3(nd * 4), dim3(256), 0, stream>>>(x, wcT, R, Wr, ba, out, d);
    }
}